// Round 14
// baseline (47.812 us; speedup 1.0000x reference)
//
#include <hip/hip_runtime.h>

#define B_TOT 16384
#define LAT   16
#define HID   256
#define STY   64
#define NS    10
#define RB    16      // rows per block (fp32 fallback path)
#define RBM   64      // rows per block (bf16 MFMA path)
#define PAD   20
#define NBK   64      // histogram blocks = B_TOT/256

// workspace layout (ints)
#define WS_CNT   0
#define WS_SEG   16
#define WS_BLK   32
#define WS_BCNT  64
#define WS_IDX   (WS_BCNT + NBK*NS)
#define IDX_CAP  (B_TOT + NS*64)
#define WS_INTS  (WS_IDX + IDX_CAP)
#define WGT_OFF_EL (((WS_INTS*4 + 255)/256)*128 + 384)
#define TOT_WEL  2334720
#define N_CHUNK  4560                    // TOT_WEL / 512

typedef __attribute__((ext_vector_type(8))) short bf16x8;
typedef __attribute__((ext_vector_type(4))) float f32x4;
typedef unsigned long long ull;

static __device__ __forceinline__ ushort f2bf(float x) {
    union { float f; unsigned u; } c; c.f = x;
    unsigned u = c.u;
    unsigned r = u + 0x7FFFu + ((u >> 16) & 1u);   // RTNE
    return (ushort)(r >> 16);
}

// ---- standalone per-block histogram (fp32 fallback path only) ----
__global__ __launch_bounds__(256) void k_blkhist(const int* __restrict__ y, int* __restrict__ ws) {
    __shared__ int h[NS];
    int t = threadIdx.x;
    if (t < NS) h[t] = 0;
    __syncthreads();
    atomicAdd(&h[y[blockIdx.x * 256 + t]], 1);
    __syncthreads();
    if (t < NS) ws[WS_BCNT + blockIdx.x * NS + t] = h[t];
}

// ---- fallback prep: per-block redundant scan + scatter ----
__global__ __launch_bounds__(256) void k_prep2(const int* __restrict__ y, int* __restrict__ ws, int rb) {
    __shared__ int tot_sh[NS], excl_sh[NS], off_sh[NS];
    const int t = threadIdx.x, wv = t >> 6, l = t & 63;
    const int myb = blockIdx.x;

    for (int s = wv; s < NS; s += 4) {
        int c = ws[WS_BCNT + l * NS + s];
        int inc = c;
        #pragma unroll
        for (int o = 1; o < 64; o <<= 1) {
            int v = __shfl_up(inc, o, 64);
            if (l >= o) inc += v;
        }
        int tot = __shfl(inc, 63, 64);
        int exc = __shfl(inc, myb, 64) - __shfl(c, myb, 64);
        if (l == 0) { tot_sh[s] = tot; excl_sh[s] = exc; }
    }
    __syncthreads();
    if (t < NS) {
        int ab = 0, ae = 0;
        for (int q = 0; q < t; ++q) {
            int cq = tot_sh[q];
            int nb = (cq + rb - 1) / rb;
            ab += nb; ae += nb * rb;
        }
        off_sh[t] = ae + excl_sh[t];
        if (myb == 0) {
            ws[WS_CNT + t] = tot_sh[t];
            ws[WS_SEG + t] = ae;
            ws[WS_BLK + t] = ab;
        }
    }
    if (myb == 0 && t == 0) {
        int ab = 0;
        for (int q = 0; q < NS; ++q) ab += (tot_sh[q] + rb - 1) / rb;
        ws[WS_BLK + NS] = ab;
    }
    __syncthreads();
    int b = myb * 256 + t;
    int p = atomicAdd(&off_sh[y[b]], 1);
    ws[WS_IDX + p] = b;
}

// ---- convert fp32 weights -> bf16 frag-linear layout (coalesced) ----
__global__ __launch_bounds__(256) void k_conv(
    const float* __restrict__ sw0, const float* __restrict__ sw1,
    const float* __restrict__ sw2, const float* __restrict__ sw3,
    const float* __restrict__ uw0, const float* __restrict__ uw1,
    const float* __restrict__ uw2, const float* __restrict__ uw3,
    ushort* __restrict__ wgt,
    const int* __restrict__ y, int* __restrict__ ws)
{
    __shared__ __align__(16) float tile[32][68];
    __shared__ int h[NS];

    if (blockIdx.x < NBK) {
        int t = threadIdx.x;
        if (t < NS) h[t] = 0;
        __syncthreads();
        atomicAdd(&h[y[blockIdx.x * 256 + t]], 1);
        __syncthreads();
        if (t < NS) ws[WS_BCNT + blockIdx.x * NS + t] = h[t];
    }

    const int t  = threadIdx.x;
    const int wv = t >> 6;
    const int l  = t & 63;
    const int lc = l & 15, lh = l >> 4;
    const int wid0 = blockIdx.x * 4;

    const float* src; int Ksrc, N, kb, nt0;
    if (wid0 < 16) {
        src = sw0; Ksrc = LAT; N = 256; kb = 0; nt0 = wid0;
    } else if (wid0 < 400) {
        int c = wid0 - 16; int ly = c >> 7; int r = c & 127;
        src = (ly == 0 ? sw1 : ly == 1 ? sw2 : sw3);
        Ksrc = 256; N = 256; kb = r >> 4; nt0 = r & 15;
    } else {
        int c = wid0 - 400; int s = c / 416; int r = c % 416;
        if (r < 384) {
            int ly = r >> 7; int rr = r & 127;
            src = (ly == 0 ? uw0 : ly == 1 ? uw1 : uw2) + (long)s * 65536;
            Ksrc = 256; N = 256; kb = rr >> 4; nt0 = rr & 15;
        } else {
            int rr = r - 384;
            src = uw3 + (long)s * 16384;
            Ksrc = 256; N = STY; kb = rr >> 2; nt0 = rr & 3;
        }
    }
    const long cbase = (long)nt0 * 16;

    #pragma unroll
    for (int it = 0; it < 2; ++it) {
        int idx = it * 256 + t;
        int row = idx >> 4;
        int c4  = (idx & 15) * 4;
        int k   = kb * 32 + row;
        float4 v = make_float4(0.f, 0.f, 0.f, 0.f);
        if (k < Ksrc) v = *(const float4*)(src + (long)k * N + cbase + c4);
        *(float4*)&tile[row][c4] = v;
    }
    __syncthreads();

    ushort v[8];
    #pragma unroll
    for (int j = 0; j < 8; ++j) v[j] = f2bf(tile[lh * 8 + j][wv * 16 + lc]);
    uint4 o;
    o.x = (unsigned)v[0] | ((unsigned)v[1] << 16);
    o.y = (unsigned)v[2] | ((unsigned)v[3] << 16);
    o.z = (unsigned)v[4] | ((unsigned)v[5] << 16);
    o.w = (unsigned)v[6] | ((unsigned)v[7] << 16);
    *(uint4*)(wgt + (long)(wid0 + wv) * 512 + l * 8) = o;
}

// ---- bf16 MFMA main kernel v14: RBM=64, 16 waves, 2nt x 2rt per wave ----
// Wave w owns cols (w&7)*32..+32 and rows (w>>3)*32..+32: per-wave LDS act
// reads HALVE (16 vs 32 b128/layer) at the cost of 2x B-frag L2 loads
// (measured cheap in r11). MFMA count and act layout unchanged.
__global__ __launch_bounds__(1024, 4) void k_main_bf(
    const float* __restrict__ z, const int* __restrict__ y,
    const int* __restrict__ ws, const ushort* __restrict__ wgt,
    const float* __restrict__ sb0, const float* __restrict__ sb1,
    const float* __restrict__ sb2, const float* __restrict__ sb3,
    const float* __restrict__ ub0, const float* __restrict__ ub1,
    const float* __restrict__ ub2, const float* __restrict__ ub3,
    float* __restrict__ out)
{
    int bid = blockIdx.x;
    {   // bijective XCD-aware swizzle (same-speaker blocks -> same XCD L2)
        int nwg = gridDim.x, q8 = nwg >> 3, r8 = nwg & 7;
        int x = bid & 7, p = bid >> 3;
        bid = (x < r8 ? x * (q8 + 1) : r8 * (q8 + 1) + (x - r8) * q8) + p;
    }

    __shared__ ushort act[2][32][RBM][8];
    __shared__ ull pk[65][3];
    __shared__ int bidx[RBM];

    const int t = threadIdx.x, w = t >> 6, l = t & 63;
    const int lc = l & 15, lh = l >> 4;
    const int nt2 = w & 7, rt2 = w >> 3;   // 2-col-tile group, 2-row-tile group

    // ---- prologue 1: wave 0 packed scan of WS_BCNT ----
    if (w == 0) {
        const int* cb = ws + WS_BCNT + l * NS;
        ull a0 = (ull)cb[0] | ((ull)cb[1] << 16) | ((ull)cb[2] << 32) | ((ull)cb[3] << 48);
        ull a1 = (ull)cb[4] | ((ull)cb[5] << 16) | ((ull)cb[6] << 32) | ((ull)cb[7] << 48);
        ull a2 = (ull)cb[8] | ((ull)cb[9] << 16);
        ull s0 = a0, s1 = a1, s2 = a2;
        #pragma unroll
        for (int o = 1; o < 64; o <<= 1) {
            ull v0 = __shfl_up(s0, o, 64);
            ull v1 = __shfl_up(s1, o, 64);
            ull v2 = __shfl_up(s2, o, 64);
            if (l >= o) { s0 += v0; s1 += v1; s2 += v2; }
        }
        pk[l][0] = s0 - a0; pk[l][1] = s1 - a1; pk[l][2] = s2 - a2;
        if (l == 63) { pk[64][0] = s0; pk[64][1] = s1; pk[64][2] = s2; }
    }
    __syncthreads();

    // ---- prologue 2: derive (s, loc, nval) from totals ----
    const ull g0 = pk[64][0], g1 = pk[64][1], g2 = pk[64][2];
    #define TOTQ(q_) ((int)((((q_) < 4) ? g0 : (((q_) < 8) ? g1 : g2)) >> (((q_) & 3) * 16)) & 0xFFFF)
    int s = -1, loc = 0, cnt = 0;
    {
        int ab = 0;
        #pragma unroll
        for (int q = 0; q < NS; ++q) {
            int tq = TOTQ(q);
            int nb = (tq + RBM - 1) >> 6;
            if (s < 0 && bid < ab + nb) { s = q; loc = bid - ab; cnt = tq; }
            ab += nb;
        }
    }
    #undef TOTQ
    if (s < 0) return;
    int nval = cnt - loc * RBM;
    if (nval > RBM) nval = RBM;
    const int lo = loc * RBM, hi = lo + RBM;
    const int sh = (s & 3) * 16;

    // ---- prologue 3: scatter from overlapping y-chunks (wave w: chunks w*4..w*4+3) ----
    #pragma unroll
    for (int bo = 0; bo < 4; ++bo) {
        int b = w * 4 + bo;
        ull pbp = (s < 4) ? pk[b][0]     : ((s < 8) ? pk[b][1]     : pk[b][2]);
        ull pnp = (s < 4) ? pk[b + 1][0] : ((s < 8) ? pk[b + 1][1] : pk[b + 1][2]);
        int Pb = (int)((pbp >> sh) & 0xFFFF);
        int Pn = (int)((pnp >> sh) & 0xFFFF);
        if (Pb < hi && Pn > lo) {
            int4 v = *(const int4*)(y + b * 256 + l * 4);
            int m0 = (v.x == s), m1 = (v.y == s), m2 = (v.z == s), m3 = (v.w == s);
            int c = m0 + m1 + m2 + m3;
            int inc = c;
            #pragma unroll
            for (int o = 1; o < 64; o <<= 1) {
                int u = __shfl_up(inc, o, 64);
                if (l >= o) inc += u;
            }
            int r  = Pb + inc - c;
            int gi = b * 256 + l * 4;
            if (m0) { if (r >= lo && r < hi) bidx[r - lo] = gi;     ++r; }
            if (m1) { if (r >= lo && r < hi) bidx[r - lo] = gi + 1; ++r; }
            if (m2) { if (r >= lo && r < hi) bidx[r - lo] = gi + 2; ++r; }
            if (m3) { if (r >= lo && r < hi) bidx[r - lo] = gi + 3; ++r; }
        }
    }
    __syncthreads();

    // ---- stage z transposed into frag layout (k 0..15 real, 16..31 zero) ----
    if (t < RBM * 4) {
        int row = t >> 2, q = t & 3;
        int gb  = (row < nval) ? bidx[row] : 0;
        float4 zv = *(const float4*)(z + (long)gb * LAT + q * 4);
        ushort4 pv; pv.x = f2bf(zv.x); pv.y = f2bf(zv.y); pv.z = f2bf(zv.z); pv.w = f2bf(zv.w);
        *(ushort4*)&act[0][q >> 1][row][(q & 1) * 4] = pv;
        ushort4 zr; zr.x = zr.y = zr.z = zr.w = 0;
        *(ushort4*)&act[0][2 + (q >> 1)][row][(q & 1) * 4] = zr;
    }
    __syncthreads();

    // ---- L0: K=32 (padded); wave w: nt {2*nt2, 2*nt2+1} x rt {2*rt2, 2*rt2+1} ----
    {
        f32x4 acc[2][2];
        #pragma unroll
        for (int q = 0; q < 2; ++q) {
            float4 bv = *(const float4*)(sb0 + (nt2 * 2 + q) * 16 + lh * 4);
            #pragma unroll
            for (int r = 0; r < 2; ++r) acc[q][r] = (f32x4){bv.x, bv.y, bv.z, bv.w};
        }
        bf16x8 Wf[2];
        #pragma unroll
        for (int q = 0; q < 2; ++q)
            Wf[q] = *(const bf16x8*)(wgt + ((nt2 * 2 + q) * 64 + l) * 8);
        #pragma unroll
        for (int r = 0; r < 2; ++r) {
            bf16x8 av = *(const bf16x8*)&act[0][lh][(rt2 * 2 + r) * 16 + lc][0];
            #pragma unroll
            for (int q = 0; q < 2; ++q)
                acc[q][r] = __builtin_amdgcn_mfma_f32_16x16x32_bf16(Wf[q], av, acc[q][r], 0, 0, 0);
        }
        #pragma unroll
        for (int q = 0; q < 2; ++q) {
            int n0 = (nt2 * 2 + q) * 16 + lh * 4;
            #pragma unroll
            for (int r = 0; r < 2; ++r) {
                ushort4 u;
                u.x = f2bf(fmaxf(acc[q][r][0], 0.f));
                u.y = f2bf(fmaxf(acc[q][r][1], 0.f));
                u.z = f2bf(fmaxf(acc[q][r][2], 0.f));
                u.w = f2bf(fmaxf(acc[q][r][3], 0.f));
                *(ushort4*)&act[1][n0 >> 3][(rt2 * 2 + r) * 16 + lc][n0 & 7] = u;
            }
        }
    }
    __syncthreads();

    auto midlayer = [&](const ushort* __restrict__ wf, const float* __restrict__ bs, int src) {
        const int dst = src ^ 1;
        f32x4 acc[2][2];
        #pragma unroll
        for (int q = 0; q < 2; ++q) {
            float4 bv = *(const float4*)(bs + (nt2 * 2 + q) * 16 + lh * 4);
            #pragma unroll
            for (int r = 0; r < 2; ++r) acc[q][r] = (f32x4){bv.x, bv.y, bv.z, bv.w};
        }
        bf16x8 Bc[2], Bn[2];
        #pragma unroll
        for (int q = 0; q < 2; ++q)
            Bc[q] = *(const bf16x8*)(wf + ((nt2 * 2 + q) * 64 + l) * 8);
        #pragma unroll
        for (int kb = 0; kb < 8; ++kb) {
            if (kb < 7) {
                #pragma unroll
                for (int q = 0; q < 2; ++q)
                    Bn[q] = *(const bf16x8*)(wf + (((kb + 1) * 16 + nt2 * 2 + q) * 64 + l) * 8);
            }
            #pragma unroll
            for (int r = 0; r < 2; ++r) {
                bf16x8 av = *(const bf16x8*)&act[src][kb * 4 + lh][(rt2 * 2 + r) * 16 + lc][0];
                #pragma unroll
                for (int q = 0; q < 2; ++q)
                    acc[q][r] = __builtin_amdgcn_mfma_f32_16x16x32_bf16(Bc[q], av, acc[q][r], 0, 0, 0);
            }
            #pragma unroll
            for (int q = 0; q < 2; ++q) Bc[q] = Bn[q];
        }
        #pragma unroll
        for (int q = 0; q < 2; ++q) {
            int n0 = (nt2 * 2 + q) * 16 + lh * 4;
            #pragma unroll
            for (int r = 0; r < 2; ++r) {
                ushort4 u;
                u.x = f2bf(fmaxf(acc[q][r][0], 0.f));
                u.y = f2bf(fmaxf(acc[q][r][1], 0.f));
                u.z = f2bf(fmaxf(acc[q][r][2], 0.f));
                u.w = f2bf(fmaxf(acc[q][r][3], 0.f));
                *(ushort4*)&act[dst][n0 >> 3][(rt2 * 2 + r) * 16 + lc][n0 & 7] = u;
            }
        }
        __syncthreads();
    };

    midlayer(wgt + 8192,   sb1, 1);
    midlayer(wgt + 73728,  sb2, 0);
    midlayer(wgt + 139264, sb3, 1);
    const long sbse = 204800 + (long)s * 212992;
    midlayer(wgt + sbse,          ub0 + s * HID, 0);
    midlayer(wgt + sbse + 65536,  ub1 + s * HID, 1);
    midlayer(wgt + sbse + 131072, ub2 + s * HID, 0);

    // ---- final: act[1] x uw3 -> out (no relu). wave w: nt=w&3, rt=w>>2 ----
    {
        const ushort* wf = wgt + sbse + 196608;
        const float*  bs = ub3 + s * STY;
        const int nt = w & 3, rt = w >> 2;
        const int n0 = nt * 16 + lh * 4;
        f32x4 acc;
        {
            float4 bv = *(const float4*)(bs + n0);
            acc = (f32x4){bv.x, bv.y, bv.z, bv.w};
        }
        bf16x8 Bc = *(const bf16x8*)(wf + (nt * 64 + l) * 8);
        bf16x8 Bn;
        #pragma unroll
        for (int kb = 0; kb < 8; ++kb) {
            if (kb < 7) Bn = *(const bf16x8*)(wf + (((kb + 1) * 4 + nt) * 64 + l) * 8);
            bf16x8 av = *(const bf16x8*)&act[1][kb * 4 + lh][rt * 16 + lc][0];
            acc = __builtin_amdgcn_mfma_f32_16x16x32_bf16(Bc, av, acc, 0, 0, 0);
            Bc = Bn;
        }
        int row = rt * 16 + lc;
        if (row < nval) {
            int gb = bidx[row];
            float4 o = make_float4(acc[0], acc[1], acc[2], acc[3]);
            *(float4*)(out + (long)gb * STY + n0) = o;
        }
    }
}

// ================= fp32 fallback (RB=16) =================
#define FMA16(wv_, hv_) do { \
    acc[0][0] = fmaf(hv_.x, wv_.x, acc[0][0]); \
    acc[0][1] = fmaf(hv_.y, wv_.x, acc[0][1]); \
    acc[0][2] = fmaf(hv_.z, wv_.x, acc[0][2]); \
    acc[0][3] = fmaf(hv_.w, wv_.x, acc[0][3]); \
    acc[1][0] = fmaf(hv_.x, wv_.y, acc[1][0]); \
    acc[1][1] = fmaf(hv_.y, wv_.y, acc[1][1]); \
    acc[1][2] = fmaf(hv_.z, wv_.y, acc[1][2]); \
    acc[1][3] = fmaf(hv_.w, wv_.y, acc[1][3]); \
    acc[2][0] = fmaf(hv_.x, wv_.z, acc[2][0]); \
    acc[2][1] = fmaf(hv_.y, wv_.z, acc[2][1]); \
    acc[2][2] = fmaf(hv_.z, wv_.z, acc[2][2]); \
    acc[2][3] = fmaf(hv_.w, wv_.z, acc[2][3]); \
    acc[3][0] = fmaf(hv_.x, wv_.w, acc[3][0]); \
    acc[3][1] = fmaf(hv_.y, wv_.w, acc[3][1]); \
    acc[3][2] = fmaf(hv_.z, wv_.w, acc[3][2]); \
    acc[3][3] = fmaf(hv_.w, wv_.w, acc[3][3]); \
} while (0)

__global__ __launch_bounds__(256, 3) void k_main_f32(
    const float* __restrict__ z,
    const int* __restrict__ ws,
    const float* __restrict__ sw0, const float* __restrict__ sb0,
    const float* __restrict__ sw1, const float* __restrict__ sb1,
    const float* __restrict__ sw2, const float* __restrict__ sb2,
    const float* __restrict__ sw3, const float* __restrict__ sb3,
    const float* __restrict__ uw0, const float* __restrict__ ub0,
    const float* __restrict__ uw1, const float* __restrict__ ub1,
    const float* __restrict__ uw2, const float* __restrict__ ub2,
    const float* __restrict__ uw3, const float* __restrict__ ub3,
    float* __restrict__ out)
{
    const int bid = blockIdx.x;
    if (bid >= ws[WS_BLK + NS]) return;
    int s = 0;
    #pragma unroll
    for (int q = 0; q < NS - 1; ++q)
        if (bid >= ws[WS_BLK + q + 1]) s = q + 1;
    const int loc  = bid - ws[WS_BLK + s];
    int nval = ws[WS_CNT + s] - loc * RB;
    if (nval > RB) nval = RB;
    const int base = ws[WS_SEG + s] + loc * RB;

    __shared__ int bidx[RB];
    __shared__ __align__(16) float zt[LAT][PAD];
    __shared__ __align__(16) float ht[2][HID][PAD];

    const int t = threadIdx.x;
    if (t < RB) {
        int gb = ws[WS_IDX + base + t];
        bidx[t] = (t < nval) ? gb : 0;
    }
    __syncthreads();
    { int r = t & (RB - 1), k = t >> 4; zt[k][r] = z[bidx[r] * LAT + k]; }
    __syncthreads();

    const int cg = t & 63, wvi = t >> 6, c0 = cg * 4, r0 = wvi * 4;
    float acc[4][4];
    {
        float4 bv = *(const float4*)(sb0 + c0);
        #pragma unroll
        for (int ri = 0; ri < 4; ++ri) { acc[0][ri] = bv.x; acc[1][ri] = bv.y; acc[2][ri] = bv.z; acc[3][ri] = bv.w; }
        #pragma unroll
        for (int k = 0; k < LAT; ++k) {
            float4 wv = *(const float4*)(sw0 + k * HID + c0);
            float4 hv = *(const float4*)(&zt[k][r0]);
            FMA16(wv, hv);
        }
        #pragma unroll
        for (int ci = 0; ci < 4; ++ci) {
            float4 v;
            v.x = fmaxf(acc[ci][0], 0.f); v.y = fmaxf(acc[ci][1], 0.f);
            v.z = fmaxf(acc[ci][2], 0.f); v.w = fmaxf(acc[ci][3], 0.f);
            *(float4*)&ht[0][c0 + ci][r0] = v;
        }
    }
    __syncthreads();

    auto midlayer = [&](const float* __restrict__ W, const float* __restrict__ bs, int src) {
        float4 bv = *(const float4*)(bs + c0);
        #pragma unroll
        for (int ri = 0; ri < 4; ++ri) { acc[0][ri] = bv.x; acc[1][ri] = bv.y; acc[2][ri] = bv.z; acc[3][ri] = bv.w; }
        #pragma unroll 4
        for (int k = 0; k < HID; ++k) {
            float4 wv = *(const float4*)(W + k * HID + c0);
            float4 hv = *(const float4*)(&ht[src][k][r0]);
            FMA16(wv, hv);
        }
        const int dst = src ^ 1;
        #pragma unroll
        for (int ci = 0; ci < 4; ++ci) {
            float4 v;
            v.x = fmaxf(acc[ci][0], 0.f); v.y = fmaxf(acc[ci][1], 0.f);
            v.z = fmaxf(acc[ci][2], 0.f); v.w = fmaxf(acc[ci][3], 0.f);
            *(float4*)&ht[dst][c0 + ci][r0] = v;
        }
    };

    midlayer(sw1, sb1, 0); __syncthreads();
    midlayer(sw2, sb2, 1); __syncthreads();
    midlayer(sw3, sb3, 0); __syncthreads();
    const long so = (long)s;
    midlayer(uw0 + so * HID * HID, ub0 + so * HID, 1); __syncthreads();
    midlayer(uw1 + so * HID * HID, ub1 + so * HID, 0); __syncthreads();
    midlayer(uw2 + so * HID * HID, ub2 + so * HID, 1); __syncthreads();

    {
        const float* W  = uw3 + so * HID * STY;
        const float* bs = ub3 + so * STY;
        const int c64 = (t & 15) * 4, rr = t >> 4;
        float4 bv = *(const float4*)(bs + c64);
        float a0 = bv.x, a1 = bv.y, a2 = bv.z, a3 = bv.w;
        #pragma unroll 4
        for (int k = 0; k < HID; ++k) {
            float4 wv = *(const float4*)(W + k * STY + c64);
            float  hv = ht[0][k][rr];
            a0 = fmaf(hv, wv.x, a0); a1 = fmaf(hv, wv.y, a1);
            a2 = fmaf(hv, wv.z, a2); a3 = fmaf(hv, wv.w, a3);
        }
        if (rr < nval) *(float4*)(out + (long)bidx[rr] * STY + c64) = make_float4(a0, a1, a2, a3);
    }
}

extern "C" void kernel_launch(void* const* d_in, const int* in_sizes, int n_in,
                              void* d_out, int out_size, void* d_ws, size_t ws_size,
                              hipStream_t stream) {
    const float* z   = (const float*)d_in[0];
    const int*   y   = (const int*)  d_in[1];
    const float* sw0 = (const float*)d_in[2];  const float* sb0 = (const float*)d_in[3];
    const float* sw1 = (const float*)d_in[4];  const float* sb1 = (const float*)d_in[5];
    const float* sw2 = (const float*)d_in[6];  const float* sb2 = (const float*)d_in[7];
    const float* sw3 = (const float*)d_in[8];  const float* sb3 = (const float*)d_in[9];
    const float* uw0 = (const float*)d_in[10]; const float* ub0 = (const float*)d_in[11];
    const float* uw1 = (const float*)d_in[12]; const float* ub1 = (const float*)d_in[13];
    const float* uw2 = (const float*)d_in[14]; const float* ub2 = (const float*)d_in[15];
    const float* uw3 = (const float*)d_in[16]; const float* ub3 = (const float*)d_in[17];
    float* out = (float*)d_out;
    int*   ws  = (int*)d_ws;

    const size_t req = (size_t)WGT_OFF_EL * 2 + (size_t)TOT_WEL * 2;
    const bool bfp = (ws_size >= req);

    if (bfp) {
        ushort* wgt = (ushort*)d_ws + WGT_OFF_EL;
        k_conv<<<N_CHUNK / 4, 256, 0, stream>>>(sw0, sw1, sw2, sw3, uw0, uw1, uw2, uw3, wgt, y, ws);
        const int nblocks = B_TOT / RBM + NS;
        k_main_bf<<<nblocks, 1024, 0, stream>>>(z, y, ws, wgt,
            sb0, sb1, sb2, sb3, ub0, ub1, ub2, ub3, out);
    } else {
        k_blkhist<<<NBK, 256, 0, stream>>>(y, ws);
        k_prep2  <<<NBK, 256, 0, stream>>>(y, ws, RB);
        const int nblocks = B_TOT / RB + NS;
        k_main_f32<<<nblocks, 256, 0, stream>>>(z, ws,
            sw0, sb0, sw1, sb1, sw2, sb2, sw3, sb3,
            uw0, ub0, uw1, ub1, uw2, ub2, uw3, ub3, out);
    }
}

// Round 15
// 39.413 us; speedup vs baseline: 1.2131x; 1.2131x over previous
//
#include <hip/hip_runtime.h>

#define B_TOT 16384
#define LAT   16
#define HID   256
#define STY   64
#define NS    10
#define RB    16      // rows per block (fp32 fallback path)
#define RBM   64      // rows per block (bf16 MFMA path)
#define PAD   20
#define NBK   64      // histogram blocks = B_TOT/256

// workspace layout (ints)
#define WS_CNT   0
#define WS_SEG   16
#define WS_BLK   32
#define WS_BCNT  64
#define WS_IDX   (WS_BCNT + NBK*NS)
#define IDX_CAP  (B_TOT + NS*64)
#define WS_INTS  (WS_IDX + IDX_CAP)
#define WGT_OFF_EL (((WS_INTS*4 + 255)/256)*128 + 384)
#define TOT_WEL  2334720
#define N_CHUNK  4560                    // TOT_WEL / 512

typedef __attribute__((ext_vector_type(8))) short bf16x8;
typedef __attribute__((ext_vector_type(4))) float f32x4;
typedef unsigned long long ull;

static __device__ __forceinline__ ushort f2bf(float x) {
    union { float f; unsigned u; } c; c.f = x;
    unsigned u = c.u;
    unsigned r = u + 0x7FFFu + ((u >> 16) & 1u);   // RTNE
    return (ushort)(r >> 16);
}

// ---- standalone per-block histogram (fp32 fallback path only) ----
__global__ __launch_bounds__(256) void k_blkhist(const int* __restrict__ y, int* __restrict__ ws) {
    __shared__ int h[NS];
    int t = threadIdx.x;
    if (t < NS) h[t] = 0;
    __syncthreads();
    atomicAdd(&h[y[blockIdx.x * 256 + t]], 1);
    __syncthreads();
    if (t < NS) ws[WS_BCNT + blockIdx.x * NS + t] = h[t];
}

// ---- fallback prep: per-block redundant scan + scatter ----
__global__ __launch_bounds__(256) void k_prep2(const int* __restrict__ y, int* __restrict__ ws, int rb) {
    __shared__ int tot_sh[NS], excl_sh[NS], off_sh[NS];
    const int t = threadIdx.x, wv = t >> 6, l = t & 63;
    const int myb = blockIdx.x;

    for (int s = wv; s < NS; s += 4) {
        int c = ws[WS_BCNT + l * NS + s];
        int inc = c;
        #pragma unroll
        for (int o = 1; o < 64; o <<= 1) {
            int v = __shfl_up(inc, o, 64);
            if (l >= o) inc += v;
        }
        int tot = __shfl(inc, 63, 64);
        int exc = __shfl(inc, myb, 64) - __shfl(c, myb, 64);
        if (l == 0) { tot_sh[s] = tot; excl_sh[s] = exc; }
    }
    __syncthreads();
    if (t < NS) {
        int ab = 0, ae = 0;
        for (int q = 0; q < t; ++q) {
            int cq = tot_sh[q];
            int nb = (cq + rb - 1) / rb;
            ab += nb; ae += nb * rb;
        }
        off_sh[t] = ae + excl_sh[t];
        if (myb == 0) {
            ws[WS_CNT + t] = tot_sh[t];
            ws[WS_SEG + t] = ae;
            ws[WS_BLK + t] = ab;
        }
    }
    if (myb == 0 && t == 0) {
        int ab = 0;
        for (int q = 0; q < NS; ++q) ab += (tot_sh[q] + rb - 1) / rb;
        ws[WS_BLK + NS] = ab;
    }
    __syncthreads();
    int b = myb * 256 + t;
    int p = atomicAdd(&off_sh[y[b]], 1);
    ws[WS_IDX + p] = b;
}

// ---- convert fp32 weights -> bf16 frag-linear layout (coalesced) ----
__global__ __launch_bounds__(256) void k_conv(
    const float* __restrict__ sw0, const float* __restrict__ sw1,
    const float* __restrict__ sw2, const float* __restrict__ sw3,
    const float* __restrict__ uw0, const float* __restrict__ uw1,
    const float* __restrict__ uw2, const float* __restrict__ uw3,
    ushort* __restrict__ wgt,
    const int* __restrict__ y, int* __restrict__ ws)
{
    __shared__ __align__(16) float tile[32][68];
    __shared__ int h[NS];

    if (blockIdx.x < NBK) {
        int t = threadIdx.x;
        if (t < NS) h[t] = 0;
        __syncthreads();
        atomicAdd(&h[y[blockIdx.x * 256 + t]], 1);
        __syncthreads();
        if (t < NS) ws[WS_BCNT + blockIdx.x * NS + t] = h[t];
    }

    const int t  = threadIdx.x;
    const int wv = t >> 6;
    const int l  = t & 63;
    const int lc = l & 15, lh = l >> 4;
    const int wid0 = blockIdx.x * 4;

    const float* src; int Ksrc, N, kb, nt0;
    if (wid0 < 16) {
        src = sw0; Ksrc = LAT; N = 256; kb = 0; nt0 = wid0;
    } else if (wid0 < 400) {
        int c = wid0 - 16; int ly = c >> 7; int r = c & 127;
        src = (ly == 0 ? sw1 : ly == 1 ? sw2 : sw3);
        Ksrc = 256; N = 256; kb = r >> 4; nt0 = r & 15;
    } else {
        int c = wid0 - 400; int s = c / 416; int r = c % 416;
        if (r < 384) {
            int ly = r >> 7; int rr = r & 127;
            src = (ly == 0 ? uw0 : ly == 1 ? uw1 : uw2) + (long)s * 65536;
            Ksrc = 256; N = 256; kb = rr >> 4; nt0 = rr & 15;
        } else {
            int rr = r - 384;
            src = uw3 + (long)s * 16384;
            Ksrc = 256; N = STY; kb = rr >> 2; nt0 = rr & 3;
        }
    }
    const long cbase = (long)nt0 * 16;

    #pragma unroll
    for (int it = 0; it < 2; ++it) {
        int idx = it * 256 + t;
        int row = idx >> 4;
        int c4  = (idx & 15) * 4;
        int k   = kb * 32 + row;
        float4 v = make_float4(0.f, 0.f, 0.f, 0.f);
        if (k < Ksrc) v = *(const float4*)(src + (long)k * N + cbase + c4);
        *(float4*)&tile[row][c4] = v;
    }
    __syncthreads();

    ushort v[8];
    #pragma unroll
    for (int j = 0; j < 8; ++j) v[j] = f2bf(tile[lh * 8 + j][wv * 16 + lc]);
    uint4 o;
    o.x = (unsigned)v[0] | ((unsigned)v[1] << 16);
    o.y = (unsigned)v[2] | ((unsigned)v[3] << 16);
    o.z = (unsigned)v[4] | ((unsigned)v[5] << 16);
    o.w = (unsigned)v[6] | ((unsigned)v[7] << 16);
    *(uint4*)(wgt + (long)(wid0 + wv) * 512 + l * 8) = o;
}

// ---- bf16 MFMA main kernel v15: r13 mapping (wave w owns nt=w, 4 rt) +
// BATCHED B-frag loads: all 8 kb frags issued before the MFMA loop, so 8
// loads/wave (128/CU) are in flight instead of 1 -> latency paid once/layer.
__global__ __launch_bounds__(1024, 4) void k_main_bf(
    const float* __restrict__ z, const int* __restrict__ y,
    const int* __restrict__ ws, const ushort* __restrict__ wgt,
    const float* __restrict__ sb0, const float* __restrict__ sb1,
    const float* __restrict__ sb2, const float* __restrict__ sb3,
    const float* __restrict__ ub0, const float* __restrict__ ub1,
    const float* __restrict__ ub2, const float* __restrict__ ub3,
    float* __restrict__ out)
{
    int bid = blockIdx.x;
    {   // bijective XCD-aware swizzle (same-speaker blocks -> same XCD L2)
        int nwg = gridDim.x, q8 = nwg >> 3, r8 = nwg & 7;
        int x = bid & 7, p = bid >> 3;
        bid = (x < r8 ? x * (q8 + 1) : r8 * (q8 + 1) + (x - r8) * q8) + p;
    }

    __shared__ ushort act[2][32][RBM][8];
    __shared__ ull pk[65][3];
    __shared__ int bidx[RBM];

    const int t = threadIdx.x, w = t >> 6, l = t & 63;
    const int lc = l & 15, lh = l >> 4;

    // ---- prologue 1: wave 0 packed scan of WS_BCNT ----
    if (w == 0) {
        const int* cb = ws + WS_BCNT + l * NS;
        ull a0 = (ull)cb[0] | ((ull)cb[1] << 16) | ((ull)cb[2] << 32) | ((ull)cb[3] << 48);
        ull a1 = (ull)cb[4] | ((ull)cb[5] << 16) | ((ull)cb[6] << 32) | ((ull)cb[7] << 48);
        ull a2 = (ull)cb[8] | ((ull)cb[9] << 16);
        ull s0 = a0, s1 = a1, s2 = a2;
        #pragma unroll
        for (int o = 1; o < 64; o <<= 1) {
            ull v0 = __shfl_up(s0, o, 64);
            ull v1 = __shfl_up(s1, o, 64);
            ull v2 = __shfl_up(s2, o, 64);
            if (l >= o) { s0 += v0; s1 += v1; s2 += v2; }
        }
        pk[l][0] = s0 - a0; pk[l][1] = s1 - a1; pk[l][2] = s2 - a2;
        if (l == 63) { pk[64][0] = s0; pk[64][1] = s1; pk[64][2] = s2; }
    }
    __syncthreads();

    // ---- prologue 2: derive (s, loc, nval) from totals ----
    const ull g0 = pk[64][0], g1 = pk[64][1], g2 = pk[64][2];
    #define TOTQ(q_) ((int)((((q_) < 4) ? g0 : (((q_) < 8) ? g1 : g2)) >> (((q_) & 3) * 16)) & 0xFFFF)
    int s = -1, loc = 0, cnt = 0;
    {
        int ab = 0;
        #pragma unroll
        for (int q = 0; q < NS; ++q) {
            int tq = TOTQ(q);
            int nb = (tq + RBM - 1) >> 6;
            if (s < 0 && bid < ab + nb) { s = q; loc = bid - ab; cnt = tq; }
            ab += nb;
        }
    }
    #undef TOTQ
    if (s < 0) return;
    int nval = cnt - loc * RBM;
    if (nval > RBM) nval = RBM;
    const int lo = loc * RBM, hi = lo + RBM;
    const int sh = (s & 3) * 16;

    // ---- prologue 3: scatter from overlapping y-chunks (wave w: chunks w*4..w*4+3) ----
    #pragma unroll
    for (int bo = 0; bo < 4; ++bo) {
        int b = w * 4 + bo;
        ull pbp = (s < 4) ? pk[b][0]     : ((s < 8) ? pk[b][1]     : pk[b][2]);
        ull pnp = (s < 4) ? pk[b + 1][0] : ((s < 8) ? pk[b + 1][1] : pk[b + 1][2]);
        int Pb = (int)((pbp >> sh) & 0xFFFF);
        int Pn = (int)((pnp >> sh) & 0xFFFF);
        if (Pb < hi && Pn > lo) {
            int4 v = *(const int4*)(y + b * 256 + l * 4);
            int m0 = (v.x == s), m1 = (v.y == s), m2 = (v.z == s), m3 = (v.w == s);
            int c = m0 + m1 + m2 + m3;
            int inc = c;
            #pragma unroll
            for (int o = 1; o < 64; o <<= 1) {
                int u = __shfl_up(inc, o, 64);
                if (l >= o) inc += u;
            }
            int r  = Pb + inc - c;
            int gi = b * 256 + l * 4;
            if (m0) { if (r >= lo && r < hi) bidx[r - lo] = gi;     ++r; }
            if (m1) { if (r >= lo && r < hi) bidx[r - lo] = gi + 1; ++r; }
            if (m2) { if (r >= lo && r < hi) bidx[r - lo] = gi + 2; ++r; }
            if (m3) { if (r >= lo && r < hi) bidx[r - lo] = gi + 3; ++r; }
        }
    }
    __syncthreads();

    // ---- stage z transposed into frag layout (k 0..15 real, 16..31 zero) ----
    if (t < RBM * 4) {
        int row = t >> 2, q = t & 3;
        int gb  = (row < nval) ? bidx[row] : 0;
        float4 zv = *(const float4*)(z + (long)gb * LAT + q * 4);
        ushort4 pv; pv.x = f2bf(zv.x); pv.y = f2bf(zv.y); pv.z = f2bf(zv.z); pv.w = f2bf(zv.w);
        *(ushort4*)&act[0][q >> 1][row][(q & 1) * 4] = pv;
        ushort4 zr; zr.x = zr.y = zr.z = zr.w = 0;
        *(ushort4*)&act[0][2 + (q >> 1)][row][(q & 1) * 4] = zr;
    }
    __syncthreads();

    // ---- L0: K=32 (padded); wave w owns nt=w, 4 row-tiles ----
    {
        f32x4 acc[4];
        const int n0 = w * 16 + lh * 4;
        {
            float4 bv = *(const float4*)(sb0 + n0);
            #pragma unroll
            for (int rt = 0; rt < 4; ++rt) acc[rt] = (f32x4){bv.x, bv.y, bv.z, bv.w};
        }
        bf16x8 Wf = *(const bf16x8*)(wgt + (w * 64 + l) * 8);
        #pragma unroll
        for (int rt = 0; rt < 4; ++rt) {
            bf16x8 av = *(const bf16x8*)&act[0][lh][rt * 16 + lc][0];
            acc[rt] = __builtin_amdgcn_mfma_f32_16x16x32_bf16(Wf, av, acc[rt], 0, 0, 0);
        }
        #pragma unroll
        for (int rt = 0; rt < 4; ++rt) {
            ushort4 u;
            u.x = f2bf(fmaxf(acc[rt][0], 0.f));
            u.y = f2bf(fmaxf(acc[rt][1], 0.f));
            u.z = f2bf(fmaxf(acc[rt][2], 0.f));
            u.w = f2bf(fmaxf(acc[rt][3], 0.f));
            *(ushort4*)&act[1][n0 >> 3][rt * 16 + lc][n0 & 7] = u;
        }
    }
    __syncthreads();

    auto midlayer = [&](const ushort* __restrict__ wf, const float* __restrict__ bs, int src) {
        const int dst = src ^ 1;
        const int n0 = w * 16 + lh * 4;
        // batched B-frag loads: all 8 kb in flight before the MFMA loop
        bf16x8 B[8];
        #pragma unroll
        for (int kb = 0; kb < 8; ++kb)
            B[kb] = *(const bf16x8*)(wf + ((kb * 16 + w) * 64 + l) * 8);
        f32x4 acc[4];
        {
            float4 bv = *(const float4*)(bs + n0);
            #pragma unroll
            for (int rt = 0; rt < 4; ++rt) acc[rt] = (f32x4){bv.x, bv.y, bv.z, bv.w};
        }
        #pragma unroll
        for (int kb = 0; kb < 8; ++kb) {
            #pragma unroll
            for (int rt = 0; rt < 4; ++rt) {
                bf16x8 av = *(const bf16x8*)&act[src][kb * 4 + lh][rt * 16 + lc][0];
                acc[rt] = __builtin_amdgcn_mfma_f32_16x16x32_bf16(B[kb], av, acc[rt], 0, 0, 0);
            }
        }
        #pragma unroll
        for (int rt = 0; rt < 4; ++rt) {
            ushort4 u;
            u.x = f2bf(fmaxf(acc[rt][0], 0.f));
            u.y = f2bf(fmaxf(acc[rt][1], 0.f));
            u.z = f2bf(fmaxf(acc[rt][2], 0.f));
            u.w = f2bf(fmaxf(acc[rt][3], 0.f));
            *(ushort4*)&act[dst][n0 >> 3][rt * 16 + lc][n0 & 7] = u;
        }
        __syncthreads();
    };

    midlayer(wgt + 8192,   sb1, 1);
    midlayer(wgt + 73728,  sb2, 0);
    midlayer(wgt + 139264, sb3, 1);
    const long sbse = 204800 + (long)s * 212992;
    midlayer(wgt + sbse,          ub0 + s * HID, 0);
    midlayer(wgt + sbse + 65536,  ub1 + s * HID, 1);
    midlayer(wgt + sbse + 131072, ub2 + s * HID, 0);

    // ---- final: act[1] x uw3 -> out (no relu). wave w: nt=w&3, rt=w>>2 ----
    {
        const ushort* wf = wgt + sbse + 196608;
        const float*  bs = ub3 + s * STY;
        const int nt = w & 3, rt = w >> 2;
        const int n0 = nt * 16 + lh * 4;
        bf16x8 B[8];
        #pragma unroll
        for (int kb = 0; kb < 8; ++kb)
            B[kb] = *(const bf16x8*)(wf + ((kb * 4 + nt) * 64 + l) * 8);
        f32x4 acc;
        {
            float4 bv = *(const float4*)(bs + n0);
            acc = (f32x4){bv.x, bv.y, bv.z, bv.w};
        }
        #pragma unroll
        for (int kb = 0; kb < 8; ++kb) {
            bf16x8 av = *(const bf16x8*)&act[1][kb * 4 + lh][rt * 16 + lc][0];
            acc = __builtin_amdgcn_mfma_f32_16x16x32_bf16(B[kb], av, acc, 0, 0, 0);
        }
        int row = rt * 16 + lc;
        if (row < nval) {
            int gb = bidx[row];
            float4 o = make_float4(acc[0], acc[1], acc[2], acc[3]);
            *(float4*)(out + (long)gb * STY + n0) = o;
        }
    }
}

// ================= fp32 fallback (RB=16) =================
#define FMA16(wv_, hv_) do { \
    acc[0][0] = fmaf(hv_.x, wv_.x, acc[0][0]); \
    acc[0][1] = fmaf(hv_.y, wv_.x, acc[0][1]); \
    acc[0][2] = fmaf(hv_.z, wv_.x, acc[0][2]); \
    acc[0][3] = fmaf(hv_.w, wv_.x, acc[0][3]); \
    acc[1][0] = fmaf(hv_.x, wv_.y, acc[1][0]); \
    acc[1][1] = fmaf(hv_.y, wv_.y, acc[1][1]); \
    acc[1][2] = fmaf(hv_.z, wv_.y, acc[1][2]); \
    acc[1][3] = fmaf(hv_.w, wv_.y, acc[1][3]); \
    acc[2][0] = fmaf(hv_.x, wv_.z, acc[2][0]); \
    acc[2][1] = fmaf(hv_.y, wv_.z, acc[2][1]); \
    acc[2][2] = fmaf(hv_.z, wv_.z, acc[2][2]); \
    acc[2][3] = fmaf(hv_.w, wv_.z, acc[2][3]); \
    acc[3][0] = fmaf(hv_.x, wv_.w, acc[3][0]); \
    acc[3][1] = fmaf(hv_.y, wv_.w, acc[3][1]); \
    acc[3][2] = fmaf(hv_.z, wv_.w, acc[3][2]); \
    acc[3][3] = fmaf(hv_.w, wv_.w, acc[3][3]); \
} while (0)

__global__ __launch_bounds__(256, 3) void k_main_f32(
    const float* __restrict__ z,
    const int* __restrict__ ws,
    const float* __restrict__ sw0, const float* __restrict__ sb0,
    const float* __restrict__ sw1, const float* __restrict__ sb1,
    const float* __restrict__ sw2, const float* __restrict__ sb2,
    const float* __restrict__ sw3, const float* __restrict__ sb3,
    const float* __restrict__ uw0, const float* __restrict__ ub0,
    const float* __restrict__ uw1, const float* __restrict__ ub1,
    const float* __restrict__ uw2, const float* __restrict__ ub2,
    const float* __restrict__ uw3, const float* __restrict__ ub3,
    float* __restrict__ out)
{
    const int bid = blockIdx.x;
    if (bid >= ws[WS_BLK + NS]) return;
    int s = 0;
    #pragma unroll
    for (int q = 0; q < NS - 1; ++q)
        if (bid >= ws[WS_BLK + q + 1]) s = q + 1;
    const int loc  = bid - ws[WS_BLK + s];
    int nval = ws[WS_CNT + s] - loc * RB;
    if (nval > RB) nval = RB;
    const int base = ws[WS_SEG + s] + loc * RB;

    __shared__ int bidx[RB];
    __shared__ __align__(16) float zt[LAT][PAD];
    __shared__ __align__(16) float ht[2][HID][PAD];

    const int t = threadIdx.x;
    if (t < RB) {
        int gb = ws[WS_IDX + base + t];
        bidx[t] = (t < nval) ? gb : 0;
    }
    __syncthreads();
    { int r = t & (RB - 1), k = t >> 4; zt[k][r] = z[bidx[r] * LAT + k]; }
    __syncthreads();

    const int cg = t & 63, wvi = t >> 6, c0 = cg * 4, r0 = wvi * 4;
    float acc[4][4];
    {
        float4 bv = *(const float4*)(sb0 + c0);
        #pragma unroll
        for (int ri = 0; ri < 4; ++ri) { acc[0][ri] = bv.x; acc[1][ri] = bv.y; acc[2][ri] = bv.z; acc[3][ri] = bv.w; }
        #pragma unroll
        for (int k = 0; k < LAT; ++k) {
            float4 wv = *(const float4*)(sw0 + k * HID + c0);
            float4 hv = *(const float4*)(&zt[k][r0]);
            FMA16(wv, hv);
        }
        #pragma unroll
        for (int ci = 0; ci < 4; ++ci) {
            float4 v;
            v.x = fmaxf(acc[ci][0], 0.f); v.y = fmaxf(acc[ci][1], 0.f);
            v.z = fmaxf(acc[ci][2], 0.f); v.w = fmaxf(acc[ci][3], 0.f);
            *(float4*)&ht[0][c0 + ci][r0] = v;
        }
    }
    __syncthreads();

    auto midlayer = [&](const float* __restrict__ W, const float* __restrict__ bs, int src) {
        float4 bv = *(const float4*)(bs + c0);
        #pragma unroll
        for (int ri = 0; ri < 4; ++ri) { acc[0][ri] = bv.x; acc[1][ri] = bv.y; acc[2][ri] = bv.z; acc[3][ri] = bv.w; }
        #pragma unroll 4
        for (int k = 0; k < HID; ++k) {
            float4 wv = *(const float4*)(W + k * HID + c0);
            float4 hv = *(const float4*)(&ht[src][k][r0]);
            FMA16(wv, hv);
        }
        const int dst = src ^ 1;
        #pragma unroll
        for (int ci = 0; ci < 4; ++ci) {
            float4 v;
            v.x = fmaxf(acc[ci][0], 0.f); v.y = fmaxf(acc[ci][1], 0.f);
            v.z = fmaxf(acc[ci][2], 0.f); v.w = fmaxf(acc[ci][3], 0.f);
            *(float4*)&ht[dst][c0 + ci][r0] = v;
        }
    };

    midlayer(sw1, sb1, 0); __syncthreads();
    midlayer(sw2, sb2, 1); __syncthreads();
    midlayer(sw3, sb3, 0); __syncthreads();
    const long so = (long)s;
    midlayer(uw0 + so * HID * HID, ub0 + so * HID, 1); __syncthreads();
    midlayer(uw1 + so * HID * HID, ub1 + so * HID, 0); __syncthreads();
    midlayer(uw2 + so * HID * HID, ub2 + so * HID, 1); __syncthreads();

    {
        const float* W  = uw3 + so * HID * STY;
        const float* bs = ub3 + so * STY;
        const int c64 = (t & 15) * 4, rr = t >> 4;
        float4 bv = *(const float4*)(bs + c64);
        float a0 = bv.x, a1 = bv.y, a2 = bv.z, a3 = bv.w;
        #pragma unroll 4
        for (int k = 0; k < HID; ++k) {
            float4 wv = *(const float4*)(W + k * STY + c64);
            float  hv = ht[0][k][rr];
            a0 = fmaf(hv, wv.x, a0); a1 = fmaf(hv, wv.y, a1);
            a2 = fmaf(hv, wv.z, a2); a3 = fmaf(hv, wv.w, a3);
        }
        if (rr < nval) *(float4*)(out + (long)bidx[rr] * STY + c64) = make_float4(a0, a1, a2, a3);
    }
}

extern "C" void kernel_launch(void* const* d_in, const int* in_sizes, int n_in,
                              void* d_out, int out_size, void* d_ws, size_t ws_size,
                              hipStream_t stream) {
    const float* z   = (const float*)d_in[0];
    const int*   y   = (const int*)  d_in[1];
    const float* sw0 = (const float*)d_in[2];  const float* sb0 = (const float*)d_in[3];
    const float* sw1 = (const float*)d_in[4];  const float* sb1 = (const float*)d_in[5];
    const float* sw2 = (const float*)d_in[6];  const float* sb2 = (const float*)d_in[7];
    const float* sw3 = (const float*)d_in[8];  const float* sb3 = (const float*)d_in[9];
    const float* uw0 = (const float*)d_in[10]; const float* ub0 = (const float*)d_in[11];
    const float* uw1 = (const float*)d_in[12]; const float* ub1 = (const float*)d_in[13];
    const float* uw2 = (const float*)d_in[14]; const float* ub2 = (const float*)d_in[15];
    const float* uw3 = (const float*)d_in[16]; const float* ub3 = (const float*)d_in[17];
    float* out = (float*)d_out;
    int*   ws  = (int*)d_ws;

    const size_t req = (size_t)WGT_OFF_EL * 2 + (size_t)TOT_WEL * 2;
    const bool bfp = (ws_size >= req);

    if (bfp) {
        ushort* wgt = (ushort*)d_ws + WGT_OFF_EL;
        k_conv<<<N_CHUNK / 4, 256, 0, stream>>>(sw0, sw1, sw2, sw3, uw0, uw1, uw2, uw3, wgt, y, ws);
        const int nblocks = B_TOT / RBM + NS;
        k_main_bf<<<nblocks, 1024, 0, stream>>>(z, y, ws, wgt,
            sb0, sb1, sb2, sb3, ub0, ub1, ub2, ub3, out);
    } else {
        k_blkhist<<<NBK, 256, 0, stream>>>(y, ws);
        k_prep2  <<<NBK, 256, 0, stream>>>(y, ws, RB);
        const int nblocks = B_TOT / RB + NS;
        k_main_f32<<<nblocks, 256, 0, stream>>>(z, ws,
            sw0, sb0, sw1, sb1, sw2, sb2, sw3, sb3,
            uw0, ub0, uw1, ub1, uw2, ub2, uw3, ub3, out);
    }
}